// Round 2
// baseline (86.017 us; speedup 1.0000x reference)
//
#include <hip/hip_runtime.h>

// Permute: out = X @ Q where Q is a one-hot permutation matrix.
// (X@Q)[b][j] = X[b][inv[j]] with inv = perm^{-1}, recovered by scanning Q.

#define FEATURES 4096
#define BATCH 8192
#define ROWS_PER_BLOCK 4
#define NBLOCKS (BATCH / ROWS_PER_BLOCK)          // 2048 = 8 blocks/CU, fully resident
#define QPT (FEATURES / 4 / 256)                  // 4 float4 quads per thread per row

// Kernel 1: scan Q (FEATURES x FEATURES, row-major) for nonzeros.
// Q[i][j] != 0  =>  perm[i] == j  =>  inv[j] = i.
// Exactly one nonzero per column => every inv[j] written exactly once per call.
__global__ __launch_bounds__(256) void build_inv_kernel(
    const float4* __restrict__ Q4, int* __restrict__ inv, int total4) {
    int idx = blockIdx.x * blockDim.x + threadIdx.x;
    int stride = gridDim.x * blockDim.x;
    for (int i = idx; i < total4; i += stride) {
        float4 v = Q4[i];
        if (v.x == 0.f && v.y == 0.f && v.z == 0.f && v.w == 0.f) continue;
        int base = i << 2;                 // flat element index
        int row  = base >> 12;             // / FEATURES (4096)
        int col  = base & (FEATURES - 1);  // % FEATURES
        if (v.x != 0.f) inv[col + 0] = row;
        if (v.y != 0.f) inv[col + 1] = row;
        if (v.z != 0.f) inv[col + 2] = row;
        if (v.w != 0.f) inv[col + 3] = row;
    }
}

// Kernel 2: each block owns 4 consecutive rows, software-pipelined:
//   stage row r in LDS (float4 writes, conflict-free ds_write_b128),
//   issue row r+1 global loads into registers,
//   gather row r from LDS -> coalesced float4 stores,
//   barrier, commit row r+1 regs -> LDS, barrier.
// HBM load latency for row r+1 hides under the gather+store of row r.
__global__ __launch_bounds__(256) void permute_rows_kernel(
    const float4* __restrict__ X4, const int4* __restrict__ inv4,
    float4* __restrict__ out4) {
    __shared__ float row[FEATURES];                // 16 KB -> 8 blocks/CU
    float4* __restrict__ row4 = (float4*)row;
    const int t = threadIdx.x;
    const size_t r0 = (size_t)blockIdx.x * ROWS_PER_BLOCK;

    // Hoist gather indices into registers (reused across all rows).
    int4 idx[QPT];
#pragma unroll
    for (int q = 0; q < QPT; ++q) idx[q] = inv4[t + q * 256];

    // Prologue: stage row r0.
    {
        const float4* __restrict__ x = X4 + r0 * (FEATURES / 4);
        float4 cur[QPT];
#pragma unroll
        for (int q = 0; q < QPT; ++q) cur[q] = x[t + q * 256];
#pragma unroll
        for (int q = 0; q < QPT; ++q) row4[t + q * 256] = cur[q];
    }
    __syncthreads();

    for (int r = 0; r < ROWS_PER_BLOCK; ++r) {
        // Issue next-row loads early; they complete under the gather below.
        float4 nxt[QPT];
        if (r + 1 < ROWS_PER_BLOCK) {
            const float4* __restrict__ x = X4 + (r0 + r + 1) * (FEATURES / 4);
#pragma unroll
            for (int q = 0; q < QPT; ++q) nxt[q] = x[t + q * 256];
        }

        // Gather row r from LDS; coalesced 16 B/lane store.
        float4* __restrict__ o = out4 + (r0 + r) * (FEATURES / 4);
#pragma unroll
        for (int q = 0; q < QPT; ++q) {
            int4 id = idx[q];
            float4 v;
            v.x = row[id.x];
            v.y = row[id.y];
            v.z = row[id.z];
            v.w = row[id.w];
            o[t + q * 256] = v;
        }

        if (r + 1 < ROWS_PER_BLOCK) {
            __syncthreads();               // all LDS reads of row r done
#pragma unroll
            for (int q = 0; q < QPT; ++q) row4[t + q * 256] = nxt[q];
            __syncthreads();               // row r+1 visible
        }
    }
}

extern "C" void kernel_launch(void* const* d_in, const int* in_sizes, int n_in,
                              void* d_out, int out_size, void* d_ws, size_t ws_size,
                              hipStream_t stream) {
    const float* X = (const float*)d_in[0];
    const float* Q = (const float*)d_in[1];
    float* out = (float*)d_out;
    int* inv = (int*)d_ws;  // 4096 ints = 16 KB scratch

    const int total4 = (FEATURES * FEATURES) / 4;  // 4M float4 quads
    build_inv_kernel<<<2048, 256, 0, stream>>>((const float4*)Q, inv, total4);
    permute_rows_kernel<<<NBLOCKS, 256, 0, stream>>>(
        (const float4*)X, (const int4*)inv, (float4*)out);
}

// Round 3
// 65.253 us; speedup vs baseline: 1.3182x; 1.3182x over previous
//
#include <hip/hip_runtime.h>

// Permute: out = X @ Q where Q is a one-hot permutation matrix.
// (X@Q)[b][j] = X[b][inv[j]] with inv = perm^{-1}, recovered by scanning Q.

#define FEATURES 4096
#define BATCH 8192
#define QPT (FEATURES / 4 / 256)   // 4 float4 quads per thread per row

typedef const __attribute__((address_space(1))) void* gptr_t;
typedef __attribute__((address_space(3))) void* lptr_t;

// Kernel 1: scan Q (FEATURES x FEATURES, row-major) for nonzeros.
// Q[i][j] != 0  =>  perm[i] == j  =>  inv[j] = i.
// Exactly one nonzero per column => every inv[j] written exactly once per call.
__global__ __launch_bounds__(256) void build_inv_kernel(
    const float4* __restrict__ Q4, int* __restrict__ inv, int total4) {
    int idx = blockIdx.x * blockDim.x + threadIdx.x;
    int stride = gridDim.x * blockDim.x;
    for (int i = idx; i < total4; i += stride) {
        float4 v = Q4[i];
        if (v.x == 0.f && v.y == 0.f && v.z == 0.f && v.w == 0.f) continue;
        int base = i << 2;                 // flat element index
        int row  = base >> 12;             // / FEATURES (4096)
        int col  = base & (FEATURES - 1);  // % FEATURES
        if (v.x != 0.f) inv[col + 0] = row;
        if (v.y != 0.f) inv[col + 1] = row;
        if (v.z != 0.f) inv[col + 2] = row;
        if (v.w != 0.f) inv[col + 3] = row;
    }
}

// Kernel 2: one row per block (8192 blocks -> full TLP, 32 waves/CU).
//  - stage the 16 KB row via global_load_lds width-16 (no VGPR round-trip,
//    linear conflict-free LDS writes)
//  - inv int4 loads issued BEFORE the barrier (L2 latency hides under staging)
//  - gather from LDS (random ~2-way conflicts, free), coalesced float4 stores
__global__ __launch_bounds__(256) void permute_row_kernel(
    const float4* __restrict__ X4, const int4* __restrict__ inv4,
    float4* __restrict__ out4) {
    __shared__ float row[FEATURES];                // 16 KB -> 8 blocks/CU (wave-cap)
    float4* row4 = (float4*)row;
    const int t = threadIdx.x;
    const size_t b = blockIdx.x;

    // Issue async staging: global -> LDS, 16 B per lane per issue.
    const float4* __restrict__ x = X4 + b * (FEATURES / 4);
#pragma unroll
    for (int q = 0; q < QPT; ++q) {
        __builtin_amdgcn_global_load_lds((gptr_t)(x + t + q * 256),
                                         (lptr_t)(row4 + t + q * 256), 16, 0, 0);
    }

    // Overlap: load gather indices (L2-resident 16 KB table) while staging flies.
    int4 idx[QPT];
#pragma unroll
    for (int q = 0; q < QPT; ++q) idx[q] = inv4[t + q * 256];

    __syncthreads();   // drains vmcnt (staging complete) + barrier

    float4* __restrict__ o = out4 + b * (FEATURES / 4);
#pragma unroll
    for (int q = 0; q < QPT; ++q) {
        int4 id = idx[q];
        float4 v;
        v.x = row[id.x];
        v.y = row[id.y];
        v.z = row[id.z];
        v.w = row[id.w];
        o[t + q * 256] = v;   // coalesced 16 B/lane store
    }
}

extern "C" void kernel_launch(void* const* d_in, const int* in_sizes, int n_in,
                              void* d_out, int out_size, void* d_ws, size_t ws_size,
                              hipStream_t stream) {
    const float* X = (const float*)d_in[0];
    const float* Q = (const float*)d_in[1];
    float* out = (float*)d_out;
    int* inv = (int*)d_ws;  // 4096 ints = 16 KB scratch

    const int total4 = (FEATURES * FEATURES) / 4;  // 4M float4 quads
    build_inv_kernel<<<2048, 256, 0, stream>>>((const float4*)Q, inv, total4);
    permute_row_kernel<<<BATCH, 256, 0, stream>>>(
        (const float4*)X, (const int4*)inv, (float4*)out);
}